// Round 4
// baseline (573.534 us; speedup 1.0000x reference)
//
#include <hip/hip_runtime.h>

// Model_65678639890860 R4: R3's chain-shortened algebra with forced
// registerization. R3 regressed (VGPR_Count=24 for ~40 live scalars ->
// compiler spilled / sank weight loads into the 4096-step serial loop).
// Fix: individually named scalars + asm register fences + launch_bounds(64,1).
//
// Math (verified in R3, absmax 6e-5):
//   gate weights pre-scaled by -log2e; c carried as cp = -L2E*c with
//   s = sqrt(1/L2E) folded into i/g biases so igp = rcp(-(s+ei)(s+eg));
//   x carried as r = w2d * 1/(1+e^{2y}) (direct gate = argmax |w2|, |cx|<=1),
//   each gate arg is ONE fma off r; wx/bl folded into tree constants.

#define L2E 1.4426950408889634f

__device__ __forceinline__ float rcp_f(float x) { return __builtin_amdgcn_rcpf(x); }
__device__ __forceinline__ float exp2_f(float x) { return __builtin_amdgcn_exp2f(x); }
__device__ __forceinline__ void pin(float& x) { asm volatile("" : "+v"(x)); }

template <int CTRL>
__device__ __forceinline__ float dpp_f(float x) {
    return __int_as_float(
        __builtin_amdgcn_mov_dpp(__float_as_int(x), CTRL, 0xF, 0xF, true));
}

__global__ __launch_bounds__(64, 1) void lstm_seq(
    const float* __restrict__ vel, const float* __restrict__ h0,
    const float* __restrict__ c0,
    const float* __restrict__ Wix, const float* __restrict__ Wih, const float* __restrict__ bi,
    const float* __restrict__ Wfx, const float* __restrict__ Wfh, const float* __restrict__ bf,
    const float* __restrict__ Wox, const float* __restrict__ Woh, const float* __restrict__ bo,
    const float* __restrict__ Wgx, const float* __restrict__ Wgh, const float* __restrict__ bg,
    const float* __restrict__ linear, const float* __restrict__ bl,
    const int* __restrict__ seqlen, float* __restrict__ out)
{
    const int lane = threadIdx.x;
    const int l = lane < 24 ? lane : 23;     // junk lanes mirror lane 23 (bounded)
    const int v = l >> 2;
    const int u = l & 3;

    const float s  = 0.83255461115769776f;   // sqrt(1/log2 e)
    const float cs = -0.26449287164720088f;  // log2(s)

    // ---- load + pre-scale all per-lane constants (named scalars only) ----
    float wi0 = -L2E * Wih[l*4+0], wi1 = -L2E * Wih[l*4+1],
          wi2 = -L2E * Wih[l*4+2], wi3 = -L2E * Wih[l*4+3];
    float wf0 = -L2E * Wfh[l*4+0], wf1 = -L2E * Wfh[l*4+1],
          wf2 = -L2E * Wfh[l*4+2], wf3 = -L2E * Wfh[l*4+3];
    float wo0 = -L2E * Woh[l*4+0], wo1 = -L2E * Woh[l*4+1],
          wo2 = -L2E * Woh[l*4+2], wo3 = -L2E * Woh[l*4+3];
    float wg0 = -L2E * Wgh[l*4+0], wg1 = -L2E * Wgh[l*4+1],
          wg2 = -L2E * Wgh[l*4+2], wg3 = -L2E * Wgh[l*4+3];

    const float wxi = -L2E * Wix[u*6+v], wxf = -L2E * Wfx[u*6+v];
    const float wxo = -L2E * Wox[u*6+v], wxg = -L2E * Wgx[u*6+v];

    float tbi = -L2E * bi[l] + wxi + cs;     // bias + wx(x-const part) + s-fold
    float tbf = -L2E * bf[l] + wxf;
    float tbo = -L2E * bo[l] + wxo;
    float tbg = -L2E * bg[l] + wxg + cs;

    const float w2i = -2.0f * wxi, w2f = -2.0f * wxf;
    const float w2o = -2.0f * wxo, w2g = -2.0f * wxg;

    // direct gate = argmax |w2|  (|cx| <= 1)
    float w2d = w2i;
    if (fabsf(w2f) > fabsf(w2d)) w2d = w2f;
    if (fabsf(w2o) > fabsf(w2d)) w2d = w2o;
    if (fabsf(w2g) > fabsf(w2d)) w2d = w2g;
    float kk  = 1.0f / w2d;
    float cxi = w2i * kk, cxf = w2f * kk, cxo = w2o * kk, cxg = w2g * kk;
    float sgn = (kk < 0.0f) ? -1.0f : 1.0f;
    const float cl = log2f(fabsf(kk));

    float lp0 = 2.0f*L2E * linear[v*4+0], lp1 = 2.0f*L2E * linear[v*4+1];
    float lp2 = 2.0f*L2E * linear[v*4+2], lp3 = 2.0f*L2E * linear[v*4+3];
    float Ky  = 2.0f*L2E * bl[v] + cl;
    const float cout = -2.0f * kk;

    float hb0 = h0[v*4+0], hb1 = h0[v*4+1], hb2 = h0[v*4+2], hb3 = h0[v*4+3];
    float cp = -L2E * c0[l];
    float r  = w2d * (0.5f * (1.0f - vel[v]));
    const int T = seqlen[0];

    // pin every loop-invariant in a VGPR: no remat, no sinking, no spills
    pin(wi0); pin(wi1); pin(wi2); pin(wi3);
    pin(wf0); pin(wf1); pin(wf2); pin(wf3);
    pin(wo0); pin(wo1); pin(wo2); pin(wo3);
    pin(wg0); pin(wg1); pin(wg2); pin(wg3);
    pin(tbi); pin(tbf); pin(tbo); pin(tbg);
    pin(cxi); pin(cxf); pin(cxo); pin(cxg);
    pin(lp0); pin(lp1); pin(lp2); pin(lp3);
    pin(Ky);  pin(kk);  pin(sgn);

#pragma unroll 4
    for (int t = 0; t < T; ++t) {
        // hdots: off-chain (ready ~40 cyc before r) — serial 4-fma, min instrs
        const float hdi = fmaf(wi3, hb3, fmaf(wi2, hb2, fmaf(wi1, hb1, fmaf(wi0, hb0, tbi))));
        const float hdf = fmaf(wf3, hb3, fmaf(wf2, hb2, fmaf(wf1, hb1, fmaf(wf0, hb0, tbf))));
        const float hdo = fmaf(wo3, hb3, fmaf(wo2, hb2, fmaf(wo1, hb1, fmaf(wo0, hb0, tbo))));
        const float hdg = fmaf(wg3, hb3, fmaf(wg2, hb2, fmaf(wg1, hb1, fmaf(wg0, hb0, tbg))));

        // x-path (critical): y-tree -> exp -> fma -> rcp
        const float p  = fmaf(lp1, hb1, fmaf(lp0, hb0, Ky));
        const float q  = fmaf(lp3, hb3, lp2 * hb2);
        const float ey = exp2_f(p + q);             // |kk| * e^{2y}
        r = rcp_f(fmaf(sgn, ey, kk));               // w2d / (1 + e^{2y})

        // gate args: one fma off r
        const float e0 = exp2_f(fmaf(cxi, r, hdi));
        const float e3 = exp2_f(fmaf(cxg, r, hdg));
        const float e1 = exp2_f(fmaf(cxf, r, hdf));
        const float e2 = exp2_f(fmaf(cxo, r, hdo));

        const float d0 = s + e0;                    // s*(1+e_i)
        const float d3 = s + e3;                    // s*(1+e_g)
        const float d1 = 1.0f + e1;                 // 1+e_f
        const float d2 = 1.0f + e2;                 // 1+e_o

        const float igp = rcp_f(-(d0 * d3));        // -L2E * sig(i)*sig(g)
        const float ft  = rcp_f(d1);
        cp = fmaf(ft, cp, igp);                     // cp = f*cp - L2E*i*g

        const float dc = 1.0f + exp2_f(cp);         // 1 + e^{-c}
        const float h  = rcp_f(d2 * dc);            // sig(o)*sig(c)

        hb0 = dpp_f<0x00>(h);
        hb1 = dpp_f<0x55>(h);
        hb2 = dpp_f<0xAA>(h);
        hb3 = dpp_f<0xFF>(h);
    }

    if (lane < 24 && u == 0) out[v] = fmaf(cout, r, 1.0f);  // tanh(y_last)
}

extern "C" void kernel_launch(void* const* d_in, const int* in_sizes, int n_in,
                              void* d_out, int out_size, void* d_ws, size_t ws_size,
                              hipStream_t stream) {
    (void)in_sizes; (void)n_in; (void)out_size; (void)d_ws; (void)ws_size;
    lstm_seq<<<1, 64, 0, stream>>>(
        (const float*)d_in[0],  (const float*)d_in[1],  (const float*)d_in[2],
        (const float*)d_in[3],  (const float*)d_in[4],  (const float*)d_in[5],
        (const float*)d_in[6],  (const float*)d_in[7],  (const float*)d_in[8],
        (const float*)d_in[9],  (const float*)d_in[10], (const float*)d_in[11],
        (const float*)d_in[12], (const float*)d_in[13], (const float*)d_in[14],
        (const float*)d_in[15], (const float*)d_in[16],
        (const int*)d_in[17],   (float*)d_out);
}

// Round 5
// 488.930 us; speedup vs baseline: 1.1730x; 1.1730x over previous
//
#include <hip/hip_runtime.h>

// Model_65678639890860 R5: packed-f32 48-lane LSTM recurrence.
// Model (fit to R1/R2/R3 within 1%): single-wave issue cadence — full-rate
// VALU = 4 cyc/instr, transcendental = 14 cyc/instr; chains/ILP irrelevant.
// => minimize wave-instruction count.
//   * v_pk_fma_f32 packs both per-lane gates (slotA, slotB) per dot term.
//   * 48-lane split (R2): gp0=(i,f), gp1=(g,o) mirrored so dpp 0x141
//     (row_half_mirror) exchanges partner values. Gate exps stay at 2.
//   * c-update as combined fraction: cp' = (cp*P - d_f)/(d_f*P), P=da*da_m
//     (s^2=ln2 fold) -> one rcp instead of two.
// Per step: 25 full-rate + 7 trans ~ 198 cyc predicted.

#define L2E 1.4426950408889634f

typedef float f32x2 __attribute__((ext_vector_type(2)));

__device__ __forceinline__ float rcp_f(float x) { return __builtin_amdgcn_rcpf(x); }
__device__ __forceinline__ float exp2_f(float x) { return __builtin_amdgcn_exp2f(x); }

template <int CTRL>
__device__ __forceinline__ float dpp_f(float x) {
    return __int_as_float(
        __builtin_amdgcn_mov_dpp(__float_as_int(x), CTRL, 0xF, 0xF, true));
}

// d = a * broadcast(b.lo) + c   (one VOP3P instruction, 2 FMAs)
__device__ __forceinline__ f32x2 pk_fma_bc1(f32x2 a, f32x2 b_lo, f32x2 c) {
    f32x2 d;
    asm("v_pk_fma_f32 %0, %1, %2, %3 op_sel:[0,0,0] op_sel_hi:[1,0,1]"
        : "=v"(d) : "v"(a), "v"(b_lo), "v"(c));
    return d;
}

__global__ __launch_bounds__(64, 1) void lstm_seq(
    const float* __restrict__ vel, const float* __restrict__ h0,
    const float* __restrict__ c0,
    const float* __restrict__ Wix, const float* __restrict__ Wih, const float* __restrict__ bi,
    const float* __restrict__ Wfx, const float* __restrict__ Wfh, const float* __restrict__ bf,
    const float* __restrict__ Wox, const float* __restrict__ Woh, const float* __restrict__ bo,
    const float* __restrict__ Wgx, const float* __restrict__ Wgh, const float* __restrict__ bg,
    const float* __restrict__ linear, const float* __restrict__ bl,
    const int* __restrict__ seqlen, float* __restrict__ out)
{
    const int lane = threadIdx.x;
    const int lc = lane < 48 ? lane : (lane - 16);  // junk octets 6,7 replay 4,5
    const int o  = lc & 7;
    const int gp = o >> 2;                 // 0: gates (i,f)   1: gates (g,o)
    const int u  = gp ? (3 - (o & 3)) : (o & 3);
    const int v  = lc >> 3;
    const int l24 = v * 4 + u;
    const bool isG0 = (gp == 0);

    const float s  = 0.83255461115769776f;   // sqrt(ln 2)   (s^2 = 1/L2E)
    const float cs = -0.26438318583f;        // log2(s)

    const float* WhA = gp ? Wgh : Wih;  const float* WhB = gp ? Woh : Wfh;
    const float* WxA = gp ? Wgx : Wix;  const float* WxB = gp ? Wox : Wfx;
    const float* bA  = gp ? bg  : bi;   const float* bB  = gp ? bo  : bf;

    // packed weights: (slotA, slotB), k-order absorbs gp1's mirrored layout
    f32x2 wh[4];
#pragma unroll
    for (int k = 0; k < 4; ++k) {
        const int ke = gp ? (3 - k) : k;     // hb_k holds h[v, ke]
        wh[k].x = -L2E * WhA[l24 * 4 + ke];
        wh[k].y = -L2E * WhB[l24 * 4 + ke];
    }
    const float wxA = -L2E * WxA[u * 6 + v];
    const float wxB = -L2E * WxB[u * 6 + v];
    f32x2 bias;
    bias.x = -L2E * bA[l24] + wxA + cs;      // slotA = i or g: both get s-fold
    bias.y = -L2E * bB[l24] + wxB;
    const float w2A = -2.0f * wxA, w2B = -2.0f * wxB;
    const float w2d = (fabsf(w2A) > fabsf(w2B)) ? w2A : w2B;  // |cx| <= 1
    const float kk  = 1.0f / w2d;
    f32x2 cx; cx.x = w2A * kk; cx.y = w2B * kk;
    const float sgn = (kk < 0.0f) ? -1.0f : 1.0f;
    const float cl  = log2f(fabsf(kk));

    float lp[4];
#pragma unroll
    for (int k = 0; k < 4; ++k) {
        const int ke = gp ? (3 - k) : k;
        lp[k] = 2.0f * L2E * linear[v * 4 + ke];
    }
    const float Ky   = 2.0f * L2E * bl[v] + cl;
    const float cout = -2.0f * kk;

    // broadcast-operand pairs: .x live, .y stale (asm reads lo only via op_sel)
    f32x2 hb0, hb1, hb2, hb3, rp;
    hb0.x = h0[v * 4 + (gp ? 3 : 0)];  hb0.y = 0.0f;
    hb1.x = h0[v * 4 + (gp ? 2 : 1)];  hb1.y = 0.0f;
    hb2.x = h0[v * 4 + (gp ? 1 : 2)];  hb2.y = 0.0f;
    hb3.x = h0[v * 4 + (gp ? 0 : 3)];  hb3.y = 0.0f;
    rp.x  = w2d * (0.5f * (1.0f - vel[v]));  rp.y = 0.0f;   // x0 = vel
    float cp = -L2E * c0[l24];
    const int T = seqlen[0];

#pragma unroll 4
    for (int t = 0; t < T; ++t) {
        // gate pre-activations, packed (A,B): 5 pk_fma
        f32x2 acc = pk_fma_bc1(wh[0], hb0, bias);
        acc = pk_fma_bc1(wh[1], hb1, acc);
        acc = pk_fma_bc1(wh[2], hb2, acc);
        acc = pk_fma_bc1(wh[3], hb3, acc);
        acc = pk_fma_bc1(cx,    rp,  acc);

        const float ea = exp2_f(acc.x);      // s * e_{i or g}
        const float eb = exp2_f(acc.y);      // e_{f or o}
        const float da = s + ea;             // s*(1 + e_A)
        const float db = 1.0f + eb;          // 1 + e_B

        const float da_m = dpp_f<0x141>(da); // partner quad's slot-A denom
        const float db_m = dpp_f<0x141>(db); // partner quad's slot-B denom

        const float P   = da * da_m;         // (1+e_i)(1+e_g)/L2E, both quads
        const float dbf = isG0 ? db : db_m;  // 1 + e_f
        const float dO  = isG0 ? db_m : db;  // 1 + e_o

        // cp' = cp/dbf - 1/P  =  (cp*P - dbf) / (dbf*P)   [cp = -L2E * c]
        const float num = fmaf(cp, P, -dbf);
        const float den = dbf * P;
        cp = num * rcp_f(den);

        const float ec   = exp2_f(cp);             // e^{-c}
        const float denh = fmaf(dO, ec, dO);       // (1+e_o)(1+e^{-c})
        const float h    = rcp_f(denh);            // sig(o)*sig(c)

        hb0.x = dpp_f<0x00>(h);
        hb1.x = dpp_f<0x55>(h);
        hb2.x = dpp_f<0xAA>(h);
        hb3.x = dpp_f<0xFF>(h);

        // m = 2*L2E*(lin.h + bl) + log2|kk|; r = w2d / (1 + e^{2y})
        const float m = fmaf(lp[0], hb0.x, fmaf(lp[1], hb1.x,
                        fmaf(lp[2], hb2.x, fmaf(lp[3], hb3.x, Ky))));
        const float ey = exp2_f(m);
        rp.x = rcp_f(fmaf(sgn, ey, kk));
    }

    if (lane < 48 && o == 0) out[v] = fmaf(cout, rp.x, 1.0f);  // tanh(y_last)
}

extern "C" void kernel_launch(void* const* d_in, const int* in_sizes, int n_in,
                              void* d_out, int out_size, void* d_ws, size_t ws_size,
                              hipStream_t stream) {
    (void)in_sizes; (void)n_in; (void)out_size; (void)d_ws; (void)ws_size;
    lstm_seq<<<1, 64, 0, stream>>>(
        (const float*)d_in[0],  (const float*)d_in[1],  (const float*)d_in[2],
        (const float*)d_in[3],  (const float*)d_in[4],  (const float*)d_in[5],
        (const float*)d_in[6],  (const float*)d_in[7],  (const float*)d_in[8],
        (const float*)d_in[9],  (const float*)d_in[10], (const float*)d_in[11],
        (const float*)d_in[12], (const float*)d_in[13], (const float*)d_in[14],
        (const float*)d_in[15], (const float*)d_in[16],
        (const int*)d_in[17],   (float*)d_out);
}

// Round 6
// 484.146 us; speedup vs baseline: 1.1846x; 1.0099x over previous
//
#include <hip/hip_runtime.h>

// Model_65678639890860 R6: chain-trimmed R5 (packed-f32, 48-lane).
// Model: single-wave issue cadence (1 slot/4cyc, trans~14) AND serial
// dependency chain both ~200-240 cyc/step; R5 measured 239 => chain-bound.
// R6: balanced m-tree (depth 20->15), sign-free direct-gate fold
// (fma(sgn,ey,kk) -> add), critical-path-first source order, unroll 8.

#define L2E 1.4426950408889634f

typedef float f32x2 __attribute__((ext_vector_type(2)));

__device__ __forceinline__ float rcp_f(float x) { return __builtin_amdgcn_rcpf(x); }
__device__ __forceinline__ float exp2_f(float x) { return __builtin_amdgcn_exp2f(x); }

template <int CTRL>
__device__ __forceinline__ float dpp_f(float x) {
    return __int_as_float(
        __builtin_amdgcn_mov_dpp(__float_as_int(x), CTRL, 0xF, 0xF, true));
}

// d = a * broadcast(b.lo) + c   (one VOP3P instruction, 2 FMAs)
__device__ __forceinline__ f32x2 pk_fma_bc1(f32x2 a, f32x2 b_lo, f32x2 c) {
    f32x2 d;
    asm("v_pk_fma_f32 %0, %1, %2, %3 op_sel:[0,0,0] op_sel_hi:[1,0,1]"
        : "=v"(d) : "v"(a), "v"(b_lo), "v"(c));
    return d;
}

__global__ __launch_bounds__(64, 1) void lstm_seq(
    const float* __restrict__ vel, const float* __restrict__ h0,
    const float* __restrict__ c0,
    const float* __restrict__ Wix, const float* __restrict__ Wih, const float* __restrict__ bi,
    const float* __restrict__ Wfx, const float* __restrict__ Wfh, const float* __restrict__ bf,
    const float* __restrict__ Wox, const float* __restrict__ Woh, const float* __restrict__ bo,
    const float* __restrict__ Wgx, const float* __restrict__ Wgh, const float* __restrict__ bg,
    const float* __restrict__ linear, const float* __restrict__ bl,
    const int* __restrict__ seqlen, float* __restrict__ out)
{
    const int lane = threadIdx.x;
    const int lc = lane < 48 ? lane : (lane - 16);  // junk octets 6,7 replay 4,5
    const int o  = lc & 7;
    const int gp = o >> 2;                 // 0: gates (i,f)   1: gates (g,o)
    const int u  = gp ? (3 - (o & 3)) : (o & 3);
    const int v  = lc >> 3;
    const int l24 = v * 4 + u;
    const bool isG0 = (gp == 0);

    const float s  = 0.83255461115769776f;   // sqrt(ln 2)   (s^2 = 1/L2E)
    const float cs = -0.26438318583f;        // log2(s)

    const float* WhA = gp ? Wgh : Wih;  const float* WhB = gp ? Woh : Wfh;
    const float* WxA = gp ? Wgx : Wix;  const float* WxB = gp ? Wox : Wfx;
    const float* bA  = gp ? bg  : bi;   const float* bB  = gp ? bo  : bf;

    // packed weights: (slotA, slotB), k-order absorbs gp1's mirrored layout
    f32x2 wh[4];
#pragma unroll
    for (int k = 0; k < 4; ++k) {
        const int ke = gp ? (3 - k) : k;     // hb_k holds h[v, ke]
        wh[k].x = -L2E * WhA[l24 * 4 + ke];
        wh[k].y = -L2E * WhB[l24 * 4 + ke];
    }
    const float wxA = -L2E * WxA[u * 6 + v];
    const float wxB = -L2E * WxB[u * 6 + v];
    f32x2 bias;
    bias.x = -L2E * bA[l24] + wxA + cs;      // slotA (i or g) gets the s-fold
    bias.y = -L2E * bB[l24] + wxB;
    const float w2A = -2.0f * wxA, w2B = -2.0f * wxB;
    // sign-free direct scale: cx*r = w2_gate/(1+e^{2y}) regardless of sign(w2d)
    const float w2d = fmaxf(fabsf(w2A), fabsf(w2B));   // > 0
    const float kk  = 1.0f / w2d;                      // > 0
    f32x2 cx; cx.x = w2A * kk; cx.y = w2B * kk;        // |cx| <= 1
    const float cl  = log2f(kk);

    float lp[4];
#pragma unroll
    for (int k = 0; k < 4; ++k) {
        const int ke = gp ? (3 - k) : k;
        lp[k] = 2.0f * L2E * linear[v * 4 + ke];
    }
    const float Ky   = 2.0f * L2E * bl[v] + cl;
    const float cout = -2.0f * kk;

    // broadcast-operand pairs: .x live, .y stale (asm reads lo via op_sel_hi)
    f32x2 hb0, hb1, hb2, hb3, rp;
    hb0.x = h0[v * 4 + (gp ? 3 : 0)];  hb0.y = 0.0f;
    hb1.x = h0[v * 4 + (gp ? 2 : 1)];  hb1.y = 0.0f;
    hb2.x = h0[v * 4 + (gp ? 1 : 2)];  hb2.y = 0.0f;
    hb3.x = h0[v * 4 + (gp ? 0 : 3)];  hb3.y = 0.0f;
    rp.x  = w2d * (0.5f * (1.0f - vel[v]));  rp.y = 0.0f;   // x0 = vel
    float cp = -L2E * c0[l24];
    const int T = seqlen[0];

#pragma unroll 8
    for (int t = 0; t < T; ++t) {
        // ---- critical path first: x-path (balanced tree, depth 3) ----
        const float p  = fmaf(lp[1], hb1.x, fmaf(lp[0], hb0.x, Ky));
        const float q  = fmaf(lp[3], hb3.x, lp[2] * hb2.x);
        const float ey = exp2_f(p + q);            // kk * e^{2y}
        rp.x = rcp_f(ey + kk);                     // w2d / (1 + e^{2y})

        // ---- gate pre-activations (hdot part has ~50cyc slack) ----
        f32x2 acc = pk_fma_bc1(wh[0], hb0, bias);
        acc = pk_fma_bc1(wh[1], hb1, acc);
        acc = pk_fma_bc1(wh[2], hb2, acc);
        acc = pk_fma_bc1(wh[3], hb3, acc);
        acc = pk_fma_bc1(cx,    rp,  acc);         // + cx * r  (on chain)

        const float ea = exp2_f(acc.x);            // s * e_{i or g}
        const float eb = exp2_f(acc.y);            // e_{f or o}
        const float da = s + ea;                   // s*(1 + e_A)
        const float db = 1.0f + eb;                // 1 + e_B

        const float da_m = dpp_f<0x141>(da);       // partner slot-A denom
        const float db_m = dpp_f<0x141>(db);       // partner slot-B denom

        const float P   = da * da_m;               // (1+e_i)(1+e_g)/L2E
        const float dbf = isG0 ? db : db_m;        // 1 + e_f
        const float dO  = isG0 ? db_m : db;        // 1 + e_o

        // cp' = cp/dbf - 1/P = (cp*P - dbf)/(dbf*P)    [cp = -L2E * c]
        const float num = fmaf(cp, P, -dbf);
        const float den = dbf * P;
        cp = num * rcp_f(den);

        const float ec   = exp2_f(cp);             // e^{-c}
        const float denh = fmaf(dO, ec, dO);       // (1+e_o)(1+e^{-c})
        const float h    = rcp_f(denh);            // sig(o)*sig(c)

        hb0.x = dpp_f<0x00>(h);
        hb1.x = dpp_f<0x55>(h);
        hb2.x = dpp_f<0xAA>(h);
        hb3.x = dpp_f<0xFF>(h);
    }

    if (lane < 48 && o == 0) out[v] = fmaf(cout, rp.x, 1.0f);  // tanh(y_last)
}

extern "C" void kernel_launch(void* const* d_in, const int* in_sizes, int n_in,
                              void* d_out, int out_size, void* d_ws, size_t ws_size,
                              hipStream_t stream) {
    (void)in_sizes; (void)n_in; (void)out_size; (void)d_ws; (void)ws_size;
    lstm_seq<<<1, 64, 0, stream>>>(
        (const float*)d_in[0],  (const float*)d_in[1],  (const float*)d_in[2],
        (const float*)d_in[3],  (const float*)d_in[4],  (const float*)d_in[5],
        (const float*)d_in[6],  (const float*)d_in[7],  (const float*)d_in[8],
        (const float*)d_in[9],  (const float*)d_in[10], (const float*)d_in[11],
        (const float*)d_in[12], (const float*)d_in[13], (const float*)d_in[14],
        (const float*)d_in[15], (const float*)d_in[16],
        (const int*)d_in[17],   (float*)d_out);
}